// Round 4
// baseline (513.385 us; speedup 1.0000x reference)
//
#include <hip/hip_runtime.h>

// CustomFourierLayer: out[b,o] = sum_{i,k} coef[o,i,k] * f_k(x[b,i])
// R4: 32x32x16 MFMA, BN=256, B in MFMA-frag layout (global->VGPR, no LDS),
// A-only LDS (8KB/step), k' = i*32 + f (feature-innermost), raw s_barrier
// with lgkmcnt-only drain (B loads stay in flight across barriers).

#define O_COLS 1024
#define I_DIM  1024
#define NF33   33
#define NSTEP  512                          // i-columns per kb half
#define CW2_ELEMS ((size_t)32 * 2048 * 512) // ob32 x kc x 512 f16 = 64 MB
#define CW2_BYTES (CW2_ELEMS * 2)

typedef _Float16 half8 __attribute__((ext_vector_type(8)));
typedef float f32x16 __attribute__((ext_vector_type(16)));
union H8 { half8 v; _Float16 h[8]; };

#define BAR() asm volatile("s_waitcnt lgkmcnt(0)\n\ts_barrier" ::: "memory")

// source k in coef's [sin1..16 | cos1..16 | 1] layout for interleaved feature f
__device__ __forceinline__ int ksrc_of(int f) {
  return (f >= 32) ? 32 : ((f >> 1) + ((f & 1) ? 16 : 0));
}

// ---------------------------------------------------------------------------
// Converter: coef f32 [o][i][k] -> Cw2 f16 in MFMA B-fragment order.
// Blob (ob32, kc) = 1KB: lane l holds 8 f16 = features f = fh*16+(l>>5)*8+e
// of column i, for col o = ob32*32 + (l&31).  kc = kb*1024 + (i&511)*2 + fh.
// One thread per (o, i): reads 33 floats, writes 4x16B (o-minor => coalesced).
// ---------------------------------------------------------------------------
__global__ __launch_bounds__(256)
void convert_coef2(const float* __restrict__ coef, _Float16* __restrict__ Cw2) {
  const int gtid = blockIdx.x * 256 + threadIdx.x;   // 1M threads
  const int o = gtid & 1023;
  const int i = gtid >> 10;

  const float* src = coef + (size_t)o * (I_DIM * NF33) + (size_t)i * NF33;
  float r[NF33];
#pragma unroll
  for (int k = 0; k < NF33; ++k) r[k] = src[k];

  const int kb = i >> 9, il = i & 511;
  const int ob32 = o >> 5;
#pragma unroll
  for (int fh = 0; fh < 2; ++fh) {
#pragma unroll
    for (int eh = 0; eh < 2; ++eh) {
      H8 h;
#pragma unroll
      for (int e = 0; e < 8; ++e)
        h.h[e] = (_Float16)r[ksrc_of(fh * 16 + eh * 8 + e)];
      const size_t blob = (size_t)ob32 * 2048 + (size_t)kb * 1024 + il * 2 + fh;
      *(half8*)(Cw2 + blob * 512 + (eh * 32 + (o & 31)) * 8) = h.v;
    }
  }
}

// bias[o] = sum_i coef[o][i][32]  (L2-warm after converter)
__global__ __launch_bounds__(256)
void bias_kernel(const float* __restrict__ coef, float* __restrict__ bias) {
  const int o = blockIdx.x, t = threadIdx.x;
  float s = 0.f;
#pragma unroll
  for (int m = 0; m < 4; ++m)
    s += coef[(size_t)o * (I_DIM * NF33) + (size_t)(t + 256 * m) * NF33 + 32];
#pragma unroll
  for (int off = 32; off > 0; off >>= 1) s += __shfl_down(s, off);
  __shared__ float ps[4];
  if ((t & 63) == 0) ps[t >> 6] = s;
  __syncthreads();
  if (t == 0) bias[o] = ps[0] + ps[1] + ps[2] + ps[3];
}

// ---------------------------------------------------------------------------
// GEMM: BM=128, BN=256, 512 threads = 8 waves (2 row x 4 col, 64x64 tiles),
// 32x32x16 f16 MFMA. Step = one i-column (32 features). Split-K x2 (kb).
// ---------------------------------------------------------------------------
__global__ __launch_bounds__(512, 2)
void fourier_gemm2(const float* __restrict__ x, const _Float16* __restrict__ Cw2,
                   const float* __restrict__ bias, float* __restrict__ out) {
  __shared__ _Float16 As[2][128 * 32];   // [buf][row][32 f16], 16 KB total

  const int tid = threadIdx.x;
  const int lane = tid & 63;
  const int wave = tid >> 6;          // 0..7
  const int wr = wave & 1;            // row half (64)
  const int wc = wave >> 1;           // col quarter (64)

  const int bid = blockIdx.x;         // 256 blocks
  const int g = bid & 7;              // (o-tile, kb) group == XCD id
  const int m0 = (bid >> 3) * 128;
  const int o_t = g & 3;
  const int kb = g >> 2;
  const int o0 = o_t * 256;

  // A staging (write): thread owns row rowW, feature-chunk jc (8 features)
  const int rowW = tid >> 2;          // 0..127
  const int jc = tid & 2 ? (tid & 3) : (tid & 3); // = tid & 3
  const int cw = (tid & 3) ^ (rowW & 3);          // swizzled 16B chunk
  const float h1f = (float)(4 * (tid & 3) + 1);   // first harmonic of this chunk

  // A frag (read) ids
  const int r32 = lane & 31;
  const int hf = lane >> 5;

  // B pointers (frag blobs, per fc)
  const int ob32 = o_t * 8 + wc * 2;
  const _Float16* pB0 = Cw2 + ((size_t)ob32 * 2048 + (size_t)kb * 1024) * 512 + lane * 8;
  const _Float16* pB1 = pB0 + (size_t)2048 * 512;

  const float* xrow = x + (size_t)(m0 + rowW) * I_DIM + kb * 512;

  f32x16 acc[2][2];
#pragma unroll
  for (int fr = 0; fr < 2; ++fr)
#pragma unroll
    for (int fc = 0; fc < 2; ++fc)
#pragma unroll
      for (int q = 0; q < 16; ++q) acc[fr][fc][q] = 0.f;
  if (kb == 0) {
#pragma unroll
    for (int fc = 0; fc < 2; ++fc) {
      const float bv = bias[o0 + wc * 64 + fc * 32 + r32];
#pragma unroll
      for (int q = 0; q < 16; ++q) { acc[0][fc][q] = bv; acc[1][fc][q] = bv; }
    }
  }

  half8 B0[4], B1[4];

  auto loadB = [&](half8* Bt, int i) {
    const size_t off = (size_t)i * 1024;
#pragma unroll
    for (int kcl = 0; kcl < 2; ++kcl) {
      Bt[kcl]     = *(const half8*)(pB0 + off + kcl * 512);
      Bt[2 + kcl] = *(const half8*)(pB1 + off + kcl * 512);
    }
  };

  // emit features jc*8 .. jc*8+7 of column t: [sin,cos] of harmonics 4jc+1..4jc+4
  auto emitA = [&](int t, int pn) {
    const float xc = xrow[t];
    float s1, c1, sb, cb;
    __sincosf(xc, &s1, &c1);
    __sincosf(h1f * xc, &sb, &cb);
    H8 h;
    h.h[0] = (_Float16)sb; h.h[1] = (_Float16)cb;
#pragma unroll
    for (int q = 1; q < 4; ++q) {
      const float ns = sb * c1 + cb * s1;
      cb = cb * c1 - sb * s1;
      sb = ns;
      h.h[2 * q] = (_Float16)sb; h.h[2 * q + 1] = (_Float16)cb;
    }
    *(half8*)&As[pn][rowW * 32 + cw * 8] = h.v;
  };

  auto compute = [&](int pn, const half8* Bt) {
    half8 af[2][2];
#pragma unroll
    for (int kcl = 0; kcl < 2; ++kcl)
#pragma unroll
      for (int fr = 0; fr < 2; ++fr) {
        const int row = wr * 64 + fr * 32 + r32;
        const int c = (kcl * 2 + hf) ^ (r32 & 3);
        af[fr][kcl] = *(const half8*)&As[pn][row * 32 + c * 8];
      }
    __builtin_amdgcn_s_setprio(1);
#pragma unroll
    for (int kcl = 0; kcl < 2; ++kcl)
#pragma unroll
      for (int fr = 0; fr < 2; ++fr)
#pragma unroll
        for (int fc = 0; fc < 2; ++fc)
          acc[fr][fc] = __builtin_amdgcn_mfma_f32_32x32x16_f16(
              af[fr][kcl], Bt[fc * 2 + kcl], acc[fr][fc], 0, 0, 0);
    __builtin_amdgcn_s_setprio(0);
  };

  // prologue: stage step 0
  emitA(0, 0);
  loadB(B0, 0);
  BAR();

#pragma unroll 1
  for (int s = 0; s < NSTEP; s += 2) {
    // even substep: consume B0/As[0]; prefetch s+1 -> B1/As[1]
    loadB(B1, s + 1);
    emitA(s + 1, 1);
    compute(0, B0);
    BAR();
    // odd substep: consume B1/As[1]; prefetch s+2 -> B0/As[0]
    if (s + 2 < NSTEP) {
      loadB(B0, s + 2);
      emitA(s + 2, 0);
    }
    compute(1, B1);
    BAR();
  }

  // epilogue: C/D 32x32 layout col=lane&31, row=(reg&3)+8*(reg>>2)+4*(lane>>5)
#pragma unroll
  for (int fr = 0; fr < 2; ++fr)
#pragma unroll
    for (int fc = 0; fc < 2; ++fc)
#pragma unroll
      for (int q = 0; q < 16; ++q) {
        const int row = m0 + wr * 64 + fr * 32 + (q & 3) + 8 * (q >> 2) + 4 * hf;
        const int col = o0 + wc * 64 + fc * 32 + r32;
        atomicAdd(&out[(size_t)row * O_COLS + col], acc[fr][fc][q]);
      }
}

// ---------------------------------------------------------------------------
// Fallback (ws too small): r3's direct-coef 16x16x32 path (no workspace).
// ---------------------------------------------------------------------------
typedef float float4v __attribute__((ext_vector_type(4)));

__global__ __launch_bounds__(512, 4)
void fourier_gemm_direct(const float* __restrict__ x, const float* __restrict__ coef,
                         float* __restrict__ out) {
  __shared__ _Float16 Asd[128 * 64];
  __shared__ _Float16 Bsd[128 * 64];

  const int tid = threadIdx.x;
  const int lane = tid & 63;
  const int wave = tid >> 6;
  const int wr = wave >> 1;
  const int wc = wave & 1;

  const int bid = blockIdx.x;
  const int o0 = (bid & 7) * 128;
  const int kb = (bid >> 3) & 1;
  const int m0 = (bid >> 4) * 128;

  const int rowA = tid >> 3;
  const int cch = tid & 7;
  const int cswz = cch ^ (rowA & 7);
  const int n1 = tid >> 3;
  const int c1q = tid & 7;
  const int r16 = lane & 15;
  const int kq = lane >> 4;

  float4v acc[2][4];
#pragma unroll
  for (int fr = 0; fr < 2; ++fr)
#pragma unroll
    for (int fc = 0; fc < 4; ++fc) acc[fr][fc] = (float4v){0.f, 0.f, 0.f, 0.f};

  float s1a[8], c1a[8], sa[8], ca[8];
  float s1b[8], c1b[8], sb[8], cb[8];

  const float* xa_base = x + (size_t)(m0 + rowA) * I_DIM + (size_t)kb * 512 + cch * 8;
  const float* xb_base = xa_base + (size_t)64 * I_DIM;

#pragma unroll 1
  for (int ib2 = 0; ib2 < 8; ++ib2) {
    {
      const float* xa = xa_base + ib2 * 64;
      const float* xb = xb_base + ib2 * 64;
      float xva[8], xvb[8];
      *(float4*)&xva[0] = *(const float4*)(xa);
      *(float4*)&xva[4] = *(const float4*)(xa + 4);
      *(float4*)&xvb[0] = *(const float4*)(xb);
      *(float4*)&xvb[4] = *(const float4*)(xb + 4);
#pragma unroll
      for (int e = 0; e < 8; ++e) {
        __sincosf(xva[e], &s1a[e], &c1a[e]); sa[e] = s1a[e]; ca[e] = c1a[e];
        __sincosf(xvb[e], &s1b[e], &c1b[e]); sb[e] = s1b[e]; cb[e] = c1b[e];
      }
    }
#pragma unroll 1
    for (int f = 0; f < NF33; ++f) {
      H8 ha, hb;
      if (f == 32) {
#pragma unroll
        for (int e = 0; e < 8; ++e) { ha.h[e] = (_Float16)1.0f; hb.h[e] = (_Float16)1.0f; }
      } else if ((f & 1) == 0) {
#pragma unroll
        for (int e = 0; e < 8; ++e) { ha.h[e] = (_Float16)sa[e]; hb.h[e] = (_Float16)sb[e]; }
      } else {
#pragma unroll
        for (int e = 0; e < 8; ++e) { ha.h[e] = (_Float16)ca[e]; hb.h[e] = (_Float16)cb[e]; }
      }
      __syncthreads();
      {
        const int ks = ksrc_of(f);
        const int ibg = kb * 8 + ib2;
        H8 b1, b2;
#pragma unroll
        for (int e = 0; e < 8; ++e) {
          const size_t ii = (size_t)(ibg * 64 + c1q * 8 + e) * NF33 + ks;
          b1.h[e] = (_Float16)coef[(size_t)(o0 + n1) * (I_DIM * NF33) + ii];
          b2.h[e] = (_Float16)coef[(size_t)(o0 + n1 + 64) * (I_DIM * NF33) + ii];
        }
        const int cs = (c1q ^ (n1 & 7)) << 3;
        *(half8*)&Bsd[n1 * 64 + cs] = b1.v;
        *(half8*)&Bsd[(n1 + 64) * 64 + cs] = b2.v;
      }
      *(half8*)&Asd[rowA * 64 + cswz * 8] = ha.v;
      *(half8*)&Asd[(rowA + 64) * 64 + cswz * 8] = hb.v;
      if ((f & 1) && (f + 2 < NF33)) {
#pragma unroll
        for (int e = 0; e < 8; ++e) {
          float ns = sa[e] * c1a[e] + ca[e] * s1a[e];
          ca[e] = ca[e] * c1a[e] - sa[e] * s1a[e]; sa[e] = ns;
          float nsb = sb[e] * c1b[e] + cb[e] * s1b[e];
          cb[e] = cb[e] * c1b[e] - sb[e] * s1b[e]; sb[e] = nsb;
        }
      }
      __syncthreads();
#pragma unroll
      for (int ksu = 0; ksu < 2; ++ksu) {
        const int ch = ((ksu << 2) + kq) ^ (r16 & 7);
        half8 af[2], bf[4];
#pragma unroll
        for (int fr = 0; fr < 2; ++fr)
          af[fr] = *(const half8*)&Asd[(wr * 32 + fr * 16 + r16) * 64 + ch * 8];
#pragma unroll
        for (int fc = 0; fc < 4; ++fc)
          bf[fc] = *(const half8*)&Bsd[(wc * 64 + fc * 16 + r16) * 64 + ch * 8];
#pragma unroll
        for (int fr = 0; fr < 2; ++fr)
#pragma unroll
          for (int fc = 0; fc < 4; ++fc)
            acc[fr][fc] = __builtin_amdgcn_mfma_f32_16x16x32_f16(
                af[fr], bf[fc], acc[fr][fc], 0, 0, 0);
      }
    }
  }
#pragma unroll
  for (int fr = 0; fr < 2; ++fr)
#pragma unroll
    for (int fc = 0; fc < 4; ++fc)
#pragma unroll
      for (int r = 0; r < 4; ++r) {
        const int row = m0 + wr * 32 + fr * 16 + kq * 4 + r;
        const int col = o0 + wc * 64 + fc * 16 + r16;
        atomicAdd(&out[(size_t)row * O_COLS + col], acc[fr][fc][r]);
      }
}

extern "C" void kernel_launch(void* const* d_in, const int* in_sizes, int n_in,
                              void* d_out, int out_size, void* d_ws, size_t ws_size,
                              hipStream_t stream) {
  const float* x = (const float*)d_in[0];
  const float* coef = (const float*)d_in[1];
  float* out = (float*)d_out;

  hipMemsetAsync(d_out, 0, (size_t)4096 * O_COLS * sizeof(float), stream);

  if (ws_size >= CW2_BYTES + O_COLS * sizeof(float)) {
    _Float16* Cw2 = (_Float16*)d_ws;
    float* bias = (float*)((char*)d_ws + CW2_BYTES);
    convert_coef2<<<dim3(4096), dim3(256), 0, stream>>>(coef, Cw2);
    bias_kernel<<<dim3(O_COLS), dim3(256), 0, stream>>>(coef, bias);
    fourier_gemm2<<<dim3(256), dim3(512), 0, stream>>>(x, Cw2, bias, out);
  } else {
    fourier_gemm_direct<<<dim3(512), dim3(512), 0, stream>>>(x, coef, out);
  }
}

// Round 5
// 408.831 us; speedup vs baseline: 1.2557x; 1.2557x over previous
//
#include <hip/hip_runtime.h>

// CustomFourierLayer: out[b,o] = sum_{i,k} coef[o,i,k] * f_k(x[b,i])
// R5: fr=4/fc=2 wave-tile (128x64), 4-wave blocks, BM=128 BN=256, split-K x4
// -> grid 512 (2 blocks/CU). A-LDS stride 80B (uniform bank classes).
// B global->VGPR in frag layout (no LDS). x prefetched 4 substeps ahead.
// Partials epilogue (no atomics) when ws permits.

#define O_COLS 1024
#define I_DIM  1024
#define NF33   33
#define B_ROWS 4096
#define CW2_ELEMS ((size_t)32 * 2048 * 512) // 64 MB f16
#define CW2_BYTES (CW2_ELEMS * 2)
#define PART_BYTES ((size_t)B_ROWS * O_COLS * sizeof(float))
#define ASTR 40   // A LDS row stride in f16 (80B = 5 x 16B units)

typedef _Float16 half8 __attribute__((ext_vector_type(8)));
typedef float f32x16 __attribute__((ext_vector_type(16)));
typedef float float4v __attribute__((ext_vector_type(4)));
union H8 { half8 v; _Float16 h[8]; };

#define BAR() asm volatile("s_waitcnt lgkmcnt(0)\n\ts_barrier" ::: "memory")

// source k in coef's [sin1..16 | cos1..16 | 1] layout for interleaved feature f
__device__ __forceinline__ int ksrc_of(int f) {
  return (f >= 32) ? 32 : ((f >> 1) + ((f & 1) ? 16 : 0));
}

// ---------------------------------------------------------------------------
// coef f32 [o][i][k] -> Cw2 f16 in 32x32x16 B-fragment blobs.
// Blob (ob32, i*2+kcl) = 1KB: lane l = kh*32 + (o&31) holds 8 f16 = features
// kcl*16 + kh*8 + e of column i, output col o = ob32*32 + (l&31).
// ---------------------------------------------------------------------------
__global__ __launch_bounds__(256)
void convert_coef2(const float* __restrict__ coef, _Float16* __restrict__ Cw2) {
  const int gtid = blockIdx.x * 256 + threadIdx.x;   // 1M threads
  const int o = gtid & 1023;
  const int i = gtid >> 10;

  const float* src = coef + (size_t)o * (I_DIM * NF33) + (size_t)i * NF33;
  float r[NF33];
#pragma unroll
  for (int k = 0; k < NF33; ++k) r[k] = src[k];

  const int ob32 = o >> 5;
#pragma unroll
  for (int kcl = 0; kcl < 2; ++kcl) {
#pragma unroll
    for (int kh = 0; kh < 2; ++kh) {
      H8 h;
#pragma unroll
      for (int e = 0; e < 8; ++e)
        h.h[e] = (_Float16)r[ksrc_of(kcl * 16 + kh * 8 + e)];
      const size_t blob = (size_t)ob32 * 2048 + (size_t)i * 2 + kcl;
      *(half8*)(Cw2 + blob * 512 + (kh * 32 + (o & 31)) * 8) = h.v;
    }
  }
}

// bias[o] = sum_i coef[o][i][32]
__global__ __launch_bounds__(256)
void bias_kernel(const float* __restrict__ coef, float* __restrict__ bias) {
  const int o = blockIdx.x, t = threadIdx.x;
  float s = 0.f;
#pragma unroll
  for (int m = 0; m < 4; ++m)
    s += coef[(size_t)o * (I_DIM * NF33) + (size_t)(t + 256 * m) * NF33 + 32];
#pragma unroll
  for (int off = 32; off > 0; off >>= 1) s += __shfl_down(s, off);
  __shared__ float ps[4];
  if ((t & 63) == 0) ps[t >> 6] = s;
  __syncthreads();
  if (t == 0) bias[o] = ps[0] + ps[1] + ps[2] + ps[3];
}

// out += p0 + p1 + p2  (4096x1024 floats, exact cover with grid 4096)
__global__ __launch_bounds__(256)
void reduce_parts(float* __restrict__ out, const float* __restrict__ p0,
                  const float* __restrict__ p1, const float* __restrict__ p2) {
  const size_t i = ((size_t)blockIdx.x * 256 + threadIdx.x) * 4;
  float4v a = *(float4v*)(out + i);
  float4v b = *(const float4v*)(p0 + i);
  float4v c = *(const float4v*)(p1 + i);
  float4v d = *(const float4v*)(p2 + i);
  *(float4v*)(out + i) = a + b + c + d;
}

// ---------------------------------------------------------------------------
// GEMM: 256 threads = 4 waves, wave-tile 128x64 (fr=4, fc=2), BM=128 BN=256,
// 32x32x16 f16 MFMA, split-K x4. Substep = one i-column (32 features).
// ---------------------------------------------------------------------------
template <bool ATOMIC>
__global__ __launch_bounds__(256, 2)
void fourier_gemm3(const float* __restrict__ x, const _Float16* __restrict__ Cw2,
                   const float* __restrict__ bias, float* __restrict__ out,
                   float* __restrict__ part) {
  __shared__ _Float16 As[2][128 * ASTR];   // 20 KB total

  const int tid = threadIdx.x;        // 0..255
  const int lane = tid & 63;
  const int wave = tid >> 6;          // 0..3 = wc

  const int bid = blockIdx.x;         // 512
  const int g = bid & 15;
  const int o_t = g & 3;
  const int kb = g >> 2;              // 0..3 (256 i-columns each)
  const int m0 = (bid >> 4) * 128;
  const int o0 = o_t * 256;

  // A-gen: thread owns row arow, chunk pair {cp, cp+2} (chunk=8 features=16B)
  const int arow = tid & 127;
  const int cp = tid >> 7;            // 0 or 1
  const float h1f = (float)(4 * cp + 1);

  // A-frag read ids
  const int r32 = lane & 31;
  const int kh = lane >> 5;

  // B pointers: wave covers cols o0 + wave*64 + fc*32
  const int ob32_0 = o_t * 8 + wave * 2;
  const _Float16* pB0 = Cw2 + ((size_t)ob32_0 * 2048 + (size_t)kb * 512) * 512 + lane * 8;
  const _Float16* pB1 = pB0 + (size_t)2048 * 512;

  const float* xrow = x + (size_t)(m0 + arow) * I_DIM + kb * 256;

  f32x16 acc[4][2];
#pragma unroll
  for (int fr = 0; fr < 4; ++fr)
#pragma unroll
    for (int fc = 0; fc < 2; ++fc)
#pragma unroll
      for (int q = 0; q < 16; ++q) acc[fr][fc][q] = 0.f;
  if (kb == 0) {
#pragma unroll
    for (int fc = 0; fc < 2; ++fc) {
      const float bv = bias[o0 + wave * 64 + fc * 32 + r32];
#pragma unroll
      for (int fr = 0; fr < 4; ++fr)
#pragma unroll
        for (int q = 0; q < 16; ++q) acc[fr][fc][q] = bv;
    }
  }

  half8 B0[4], B1[4];

  auto loadB = [&](half8* Bt, int s) {    // s = local substep 0..255
    const size_t base = (size_t)(s * 2) * 512;
    Bt[0] = *(const half8*)(pB0 + base);
    Bt[1] = *(const half8*)(pB0 + base + 512);
    Bt[2] = *(const half8*)(pB1 + base);
    Bt[3] = *(const half8*)(pB1 + base + 512);
  };

  auto emitA = [&](float xv, int pn) {
    float s1, c1, sa, ca;
    __sincosf(xv, &s1, &c1);
    __sincosf(h1f * xv, &sa, &ca);
    // chunk cp: harmonics 4cp+1..4cp+4
    {
      H8 h;
      float s = sa, c = ca;
      h.h[0] = (_Float16)s; h.h[1] = (_Float16)c;
#pragma unroll
      for (int q = 1; q < 4; ++q) {
        const float ns = s * c1 + c * s1;
        c = c * c1 - s * s1;
        s = ns;
        h.h[2 * q] = (_Float16)s; h.h[2 * q + 1] = (_Float16)c;
      }
      *(half8*)&As[pn][arow * ASTR + cp * 8] = h.v;
    }
    // (s8, c8) by doubling, then chunk cp+2: harmonics 4cp+9..4cp+12
    {
      const float s2 = 2.f * s1 * c1, c2 = 2.f * c1 * c1 - 1.f;
      const float s4 = 2.f * s2 * c2, c4 = 2.f * c2 * c2 - 1.f;
      const float s8 = 2.f * s4 * c4, c8 = 2.f * c4 * c4 - 1.f;
      H8 h;
      float s = sa * c8 + ca * s8;
      float c = ca * c8 - sa * s8;
      h.h[0] = (_Float16)s; h.h[1] = (_Float16)c;
#pragma unroll
      for (int q = 1; q < 4; ++q) {
        const float ns = s * c1 + c * s1;
        c = c * c1 - s * s1;
        s = ns;
        h.h[2 * q] = (_Float16)s; h.h[2 * q + 1] = (_Float16)c;
      }
      *(half8*)&As[pn][arow * ASTR + (cp + 2) * 8] = h.v;
    }
  };

  auto compute = [&](int pn, const half8* Bt) {
    half8 af[4][2];
#pragma unroll
    for (int fr = 0; fr < 4; ++fr)
#pragma unroll
      for (int kcl = 0; kcl < 2; ++kcl)
        af[fr][kcl] = *(const half8*)&As[pn][(fr * 32 + r32) * ASTR + (kcl * 2 + kh) * 8];
    __builtin_amdgcn_s_setprio(1);
#pragma unroll
    for (int kcl = 0; kcl < 2; ++kcl)
#pragma unroll
      for (int fr = 0; fr < 4; ++fr)
#pragma unroll
        for (int fc = 0; fc < 2; ++fc)
          acc[fr][fc] = __builtin_amdgcn_mfma_f32_32x32x16_f16(
              af[fr][kcl], Bt[fc * 2 + kcl], acc[fr][fc], 0, 0, 0);
    __builtin_amdgcn_s_setprio(0);
  };

  // prologue
  float4 xq = *(const float4*)(xrow);
  emitA(xq.x, 0);
  loadB(B0, 0);
  BAR();

#pragma unroll 1
  for (int sg = 0; sg < 256; sg += 4) {
    const bool more = (sg + 4 < 256);
    const float4 xqn = more ? *(const float4*)(xrow + sg + 4) : xq;

    loadB(B1, sg + 1); emitA(xq.y, 1);
    compute(0, B0); BAR();

    loadB(B0, sg + 2); emitA(xq.z, 0);
    compute(1, B1); BAR();

    loadB(B1, sg + 3); emitA(xq.w, 1);
    compute(0, B0); BAR();

    if (more) { loadB(B0, sg + 4); emitA(xqn.x, 0); }
    compute(1, B1); BAR();

    xq = xqn;
  }

  // epilogue: C/D 32x32 layout col=lane&31, row=(q&3)+8*(q>>2)+4*(lane>>5)
  float* dst;
  if (ATOMIC) dst = out;
  else dst = (kb == 0) ? out : part + (size_t)(kb - 1) * (B_ROWS * O_COLS);
#pragma unroll
  for (int fr = 0; fr < 4; ++fr)
#pragma unroll
    for (int fc = 0; fc < 2; ++fc)
#pragma unroll
      for (int q = 0; q < 16; ++q) {
        const int row = m0 + fr * 32 + (q & 3) + 8 * (q >> 2) + 4 * kh;
        const int col = o0 + wave * 64 + fc * 32 + r32;
        if (ATOMIC) atomicAdd(&dst[(size_t)row * O_COLS + col], acc[fr][fc][q]);
        else dst[(size_t)row * O_COLS + col] = acc[fr][fc][q];
      }
}

// ---------------------------------------------------------------------------
// Fallback (ws too small): direct-coef 16x16x32 path (no workspace).
// ---------------------------------------------------------------------------
__global__ __launch_bounds__(512, 4)
void fourier_gemm_direct(const float* __restrict__ x, const float* __restrict__ coef,
                         float* __restrict__ out) {
  __shared__ _Float16 Asd[128 * 64];
  __shared__ _Float16 Bsd[128 * 64];

  const int tid = threadIdx.x;
  const int lane = tid & 63;
  const int wave = tid >> 6;
  const int wr = wave >> 1;
  const int wc = wave & 1;

  const int bid = blockIdx.x;
  const int o0 = (bid & 7) * 128;
  const int kb = (bid >> 3) & 1;
  const int m0 = (bid >> 4) * 128;

  const int rowA = tid >> 3;
  const int cch = tid & 7;
  const int cswz = cch ^ (rowA & 7);
  const int n1 = tid >> 3;
  const int c1q = tid & 7;
  const int r16 = lane & 15;
  const int kq = lane >> 4;

  float4v acc[2][4];
#pragma unroll
  for (int fr = 0; fr < 2; ++fr)
#pragma unroll
    for (int fc = 0; fc < 4; ++fc) acc[fr][fc] = (float4v){0.f, 0.f, 0.f, 0.f};

  float s1a[8], c1a[8], sa[8], ca[8];
  float s1b[8], c1b[8], sb[8], cb[8];

  const float* xa_base = x + (size_t)(m0 + rowA) * I_DIM + (size_t)kb * 512 + cch * 8;
  const float* xb_base = xa_base + (size_t)64 * I_DIM;

#pragma unroll 1
  for (int ib2 = 0; ib2 < 8; ++ib2) {
    {
      const float* xa = xa_base + ib2 * 64;
      const float* xb = xb_base + ib2 * 64;
      float xva[8], xvb[8];
      *(float4*)&xva[0] = *(const float4*)(xa);
      *(float4*)&xva[4] = *(const float4*)(xa + 4);
      *(float4*)&xvb[0] = *(const float4*)(xb);
      *(float4*)&xvb[4] = *(const float4*)(xb + 4);
#pragma unroll
      for (int e = 0; e < 8; ++e) {
        __sincosf(xva[e], &s1a[e], &c1a[e]); sa[e] = s1a[e]; ca[e] = c1a[e];
        __sincosf(xvb[e], &s1b[e], &c1b[e]); sb[e] = s1b[e]; cb[e] = c1b[e];
      }
    }
#pragma unroll 1
    for (int f = 0; f < NF33; ++f) {
      H8 ha, hb;
      if (f == 32) {
#pragma unroll
        for (int e = 0; e < 8; ++e) { ha.h[e] = (_Float16)1.0f; hb.h[e] = (_Float16)1.0f; }
      } else if ((f & 1) == 0) {
#pragma unroll
        for (int e = 0; e < 8; ++e) { ha.h[e] = (_Float16)sa[e]; hb.h[e] = (_Float16)sb[e]; }
      } else {
#pragma unroll
        for (int e = 0; e < 8; ++e) { ha.h[e] = (_Float16)ca[e]; hb.h[e] = (_Float16)cb[e]; }
      }
      __syncthreads();
      {
        const int ks = ksrc_of(f);
        const int ibg = kb * 8 + ib2;
        H8 b1, b2;
#pragma unroll
        for (int e = 0; e < 8; ++e) {
          const size_t ii = (size_t)(ibg * 64 + c1q * 8 + e) * NF33 + ks;
          b1.h[e] = (_Float16)coef[(size_t)(o0 + n1) * (I_DIM * NF33) + ii];
          b2.h[e] = (_Float16)coef[(size_t)(o0 + n1 + 64) * (I_DIM * NF33) + ii];
        }
        const int cs = (c1q ^ (n1 & 7)) << 3;
        *(half8*)&Bsd[n1 * 64 + cs] = b1.v;
        *(half8*)&Bsd[(n1 + 64) * 64 + cs] = b2.v;
      }
      *(half8*)&Asd[rowA * 64 + cswz * 8] = ha.v;
      *(half8*)&Asd[(rowA + 64) * 64 + cswz * 8] = hb.v;
      if ((f & 1) && (f + 2 < NF33)) {
#pragma unroll
        for (int e = 0; e < 8; ++e) {
          float ns = sa[e] * c1a[e] + ca[e] * s1a[e];
          ca[e] = ca[e] * c1a[e] - sa[e] * s1a[e]; sa[e] = ns;
          float nsb = sb[e] * c1b[e] + cb[e] * s1b[e];
          cb[e] = cb[e] * c1b[e] - sb[e] * s1b[e]; sb[e] = nsb;
        }
      }
      __syncthreads();
#pragma unroll
      for (int ksu = 0; ksu < 2; ++ksu) {
        const int ch = ((ksu << 2) + kq) ^ (r16 & 7);
        half8 af[2], bf[4];
#pragma unroll
        for (int fr = 0; fr < 2; ++fr)
          af[fr] = *(const half8*)&Asd[(wr * 32 + fr * 16 + r16) * 64 + ch * 8];
#pragma unroll
        for (int fc = 0; fc < 4; ++fc)
          bf[fc] = *(const half8*)&Bsd[(wc * 64 + fc * 16 + r16) * 64 + ch * 8];
#pragma unroll
        for (int fr = 0; fr < 2; ++fr)
#pragma unroll
          for (int fc = 0; fc < 4; ++fc)
            acc[fr][fc] = __builtin_amdgcn_mfma_f32_16x16x32_f16(
                af[fr], bf[fc], acc[fr][fc], 0, 0, 0);
      }
    }
  }
#pragma unroll
  for (int fr = 0; fr < 2; ++fr)
#pragma unroll
    for (int fc = 0; fc < 4; ++fc)
#pragma unroll
      for (int r = 0; r < 4; ++r) {
        const int row = m0 + wr * 32 + fr * 16 + kq * 4 + r;
        const int col = o0 + wc * 64 + fc * 16 + r16;
        atomicAdd(&out[(size_t)row * O_COLS + col], acc[fr][fc][r]);
      }
}

extern "C" void kernel_launch(void* const* d_in, const int* in_sizes, int n_in,
                              void* d_out, int out_size, void* d_ws, size_t ws_size,
                              hipStream_t stream) {
  const float* x = (const float*)d_in[0];
  const float* coef = (const float*)d_in[1];
  float* out = (float*)d_out;

  const size_t need_parts = CW2_BYTES + 4096 + 3 * PART_BYTES;
  const size_t need_atomic = CW2_BYTES + 4096;

  if (ws_size >= need_parts) {
    _Float16* Cw2 = (_Float16*)d_ws;
    float* bias = (float*)((char*)d_ws + CW2_BYTES);
    float* part = (float*)((char*)d_ws + CW2_BYTES + 4096);
    convert_coef2<<<dim3(4096), dim3(256), 0, stream>>>(coef, Cw2);
    bias_kernel<<<dim3(O_COLS), dim3(256), 0, stream>>>(coef, bias);
    fourier_gemm3<false><<<dim3(512), dim3(256), 0, stream>>>(x, Cw2, bias, out, part);
    reduce_parts<<<dim3(4096), dim3(256), 0, stream>>>(
        out, part, part + (size_t)B_ROWS * O_COLS, part + (size_t)2 * B_ROWS * O_COLS);
  } else if (ws_size >= need_atomic) {
    _Float16* Cw2 = (_Float16*)d_ws;
    float* bias = (float*)((char*)d_ws + CW2_BYTES);
    hipMemsetAsync(out, 0, (size_t)B_ROWS * O_COLS * sizeof(float), stream);
    convert_coef2<<<dim3(4096), dim3(256), 0, stream>>>(coef, Cw2);
    bias_kernel<<<dim3(O_COLS), dim3(256), 0, stream>>>(coef, bias);
    fourier_gemm3<true><<<dim3(512), dim3(256), 0, stream>>>(x, Cw2, bias, out, nullptr);
  } else {
    hipMemsetAsync(out, 0, (size_t)B_ROWS * O_COLS * sizeof(float), stream);
    fourier_gemm_direct<<<dim3(512), dim3(512), 0, stream>>>(x, coef, out);
  }
}